// Round 2
// baseline (6881.647 us; speedup 1.0000x reference)
//
#include <hip/hip_runtime.h>
#include <stdint.h>

typedef __bf16 bf16x8 __attribute__((ext_vector_type(8)));
typedef float f32x4 __attribute__((ext_vector_type(4)));

#define MFMA16(a, b, c) __builtin_amdgcn_mfma_f32_16x16x32_bf16((a), (b), (c), 0, 0, 0)

__device__ __forceinline__ float sigf(float x) { return 1.f / (1.f + __expf(-x)); }
__device__ __forceinline__ float tanhfast(float x) { return 1.f - 2.f / (__expf(2.f * x) + 1.f); }
__device__ __forceinline__ float bf2f(uint16_t u) {
  union { float f; uint32_t i; } v; v.i = ((uint32_t)u) << 16; return v.f;
}
__device__ __forceinline__ uint16_t f2bf(float f) {
  union { float f; uint32_t i; } v; v.f = f;
  return (uint16_t)((v.i + 0x7FFFu + ((v.i >> 16) & 1u)) >> 16);
}
// 8 consecutive f32 -> bf16x8 (RNE); p must be 16B-aligned
__device__ __forceinline__ bf16x8 cvt8(const float* __restrict__ p) {
  f32x4 a = *(const f32x4*)p;
  f32x4 b = *(const f32x4*)(p + 4);
  bf16x8 r;
  r[0] = (__bf16)a[0]; r[1] = (__bf16)a[1]; r[2] = (__bf16)a[2]; r[3] = (__bf16)a[3];
  r[4] = (__bf16)b[0]; r[5] = (__bf16)b[1]; r[6] = (__bf16)b[2]; r[7] = (__bf16)b[3];
  return r;
}

// ---------------------------------------------------------------------------
// K0: mf_W f32 [512][1000] -> bf16 padded [512][1024] (pad k>=1000 with 0)
// ---------------------------------------------------------------------------
__global__ __launch_bounds__(256) void k_prep(
    const float* __restrict__ mf_W, uint16_t* __restrict__ mfWb) {
  const int idx = blockIdx.x * 256 + threadIdx.x;   // 524288 total
  const int h = idx >> 10, k = idx & 1023;
  const float v = (k < 1000) ? mf_W[(size_t)h * 1000 + k] : 0.f;
  mfWb[idx] = f2bf(v);
}

// ---------------------------------------------------------------------------
// K1: encW[v][col] = sum_k enc_emb[v][k]*W_ih[col][k] + b_ih[col] + b_hh[col]
//     M=1002, N=2048, K=512. f32 in (cvt to bf16), f32 out.
// ---------------------------------------------------------------------------
__global__ __launch_bounds__(256) void k_encW(
    const float* __restrict__ enc_emb,   // [1002][512]
    const float* __restrict__ W_ih,      // [2048][512]
    const float* __restrict__ b_ih,
    const float* __restrict__ b_hh,
    float* __restrict__ encW)            // [1002][2048]
{
  const int w = threadIdx.x >> 6, l = threadIdx.x & 63;
  const int mblk = blockIdx.x & 15;   // 16 M-blocks of 64 rows
  const int nblk = blockIdx.x >> 4;   // 32 N-blocks of 64 cols
  const int kg = l >> 4;
  const int arow = mblk * 64 + w * 16 + (l & 15);
  const bool rowok = arow < 1002;

  f32x4 acc[4] = {};
  for (int kk = 0; kk < 16; ++kk) {
    const int kc = kk * 32 + kg * 8;
    bf16x8 a = {};
    if (rowok) a = cvt8(enc_emb + (size_t)arow * 512 + kc);
#pragma unroll
    for (int n = 0; n < 4; ++n) {
      const int wrow = nblk * 64 + n * 16 + (l & 15);
      bf16x8 b = cvt8(W_ih + (size_t)wrow * 512 + kc);
      acc[n] = MFMA16(a, b, acc[n]);
    }
  }
  const int orow = mblk * 64 + w * 16 + kg * 4;
#pragma unroll
  for (int n = 0; n < 4; ++n) {
    const int col = nblk * 64 + n * 16 + (l & 15);
    const float bias = b_ih[col] + b_hh[col];
#pragma unroll
    for (int j = 0; j < 4; ++j) {
      const int rrow = orow + j;
      if (rrow < 1002) encW[(size_t)rrow * 2048 + col] = acc[n][j] + bias;
    }
  }
}

// ---------------------------------------------------------------------------
// K2: ext[m][h] = sum_f ev[m][f]*mf_W[h][f] + mf_b[h]
//     ev[m] = concat(user_emb[uid[m]](500), skill_emb[sid[m]](500)), f32.
//     Block = 64 rows x 512 cols; A staged f32->bf16 in LDS (stride 80B),
//     B = pre-converted bf16 mfWb (L2-resident). M=51200, K=1024 (padded).
// ---------------------------------------------------------------------------
__global__ __launch_bounds__(256, 1) void k_ext(
    const int* __restrict__ uid, const int* __restrict__ sid,   // [51200]
    const float* __restrict__ user_emb,    // [50000][500]
    const float* __restrict__ skill_emb,   // [500][500]
    const uint16_t* __restrict__ mfWb,     // [512][1024] bf16
    const float* __restrict__ mf_b,        // [512]
    uint16_t* __restrict__ ext)            // [51200][512] bf16
{
  __shared__ uint16_t As[64 * 40];   // 64 rows, stride 40 bf16 (80B)

  const int tid = threadIdx.x;
  const int w = tid >> 6, l = tid & 63, kg = l >> 4;
  const int mblk = blockIdx.x;

  // staging role: 4 threads per row, 8 f32 each
  const int srow = tid >> 2;
  const int kq = (tid & 3) * 8;
  const int m = mblk * 64 + srow;
  const float* up = user_emb + (size_t)uid[m] * 500;
  const float* sp = skill_emb + (size_t)sid[m] * 500;

  f32x4 acc[4][8] = {};

  for (int kk = 0; kk < 32; ++kk) {
    const int e0 = kk * 32 + kq;
    bf16x8 av = {};
    if (e0 + 8 <= 500) {                       // fully user
      av = cvt8(up + e0);
    } else if (e0 == 496) {                    // straddle 496..503
      f32x4 a4 = *(const f32x4*)(up + 496);
      f32x4 b4 = *(const f32x4*)sp;
      av[0] = (__bf16)a4[0]; av[1] = (__bf16)a4[1]; av[2] = (__bf16)a4[2]; av[3] = (__bf16)a4[3];
      av[4] = (__bf16)b4[0]; av[5] = (__bf16)b4[1]; av[6] = (__bf16)b4[2]; av[7] = (__bf16)b4[3];
    } else if (e0 < 1000) {                    // fully skill (16B-aligned)
      av = cvt8(sp + (e0 - 500));
    }                                          // e0 >= 1000: zero pad
    *(bf16x8*)((char*)As + srow * 80 + kq * 2) = av;
    __syncthreads();

    bf16x8 a[4];
#pragma unroll
    for (int rf = 0; rf < 4; ++rf)
      a[rf] = *(const bf16x8*)((char*)As + (rf * 16 + (l & 15)) * 80 + kg * 16);
#pragma unroll
    for (int n = 0; n < 8; ++n) {
      const int col = w * 128 + n * 16 + (l & 15);
      bf16x8 b = *(const bf16x8*)(mfWb + (size_t)col * 1024 + kk * 32 + kg * 8);
#pragma unroll
      for (int rf = 0; rf < 4; ++rf)
        acc[rf][n] = MFMA16(a[rf], b, acc[rf][n]);
    }
    __syncthreads();
  }

#pragma unroll
  for (int rf = 0; rf < 4; ++rf)
#pragma unroll
    for (int n = 0; n < 8; ++n) {
      const int col = w * 128 + n * 16 + (l & 15);
      const float bias = mf_b[col];
#pragma unroll
      for (int j = 0; j < 4; ++j) {
        const int grow = mblk * 64 + rf * 16 + kg * 4 + j;
        ext[(size_t)grow * 512 + col] = f2bf(acc[rf][n][j] + bias);
      }
    }
}

// ---------------------------------------------------------------------------
// K3: persistent LSTM scan. grid = 16 rowgroups x 16 h-slices. Block (r,c):
//     W_hh slice (4 gates x 32 h x 512, cvt'd to bf16) in REGISTERS; ht
//     exchanged through L3 with agent-scope atomics; per-step 16-peer
//     rowgroup barrier (monotonic counter, zeroed by pre-launch memset).
// ---------------------------------------------------------------------------
__global__ __launch_bounds__(256, 1) void k_scan(
    const int* __restrict__ inp,        // [256][200]
    const float* __restrict__ W_hh,     // [2048][512] f32
    const float* __restrict__ encW,     // [1002][2048] f32
    const uint16_t* __restrict__ ext,   // [256*200][512] bf16
    uint16_t* __restrict__ hbuf,        // [2][256][512] bf16 (buf0 zeroed)
    float* __restrict__ hfinal,         // [256][512] f32
    uint32_t* __restrict__ cnt)         // [16]
{
  __shared__ uint16_t htgS[16 * 512];   // XOR-swizzled rows of 1024B
  __shared__ float gbuf[4][16][32];
  __shared__ float ctS[16][32];

  const int tid = threadIdx.x;
  const int w = tid >> 6, l = tid & 63;   // wave w = gate (i,f,g,o)
  const int c = blockIdx.x & 15;          // h-slice (32 h)
  const int r = blockIdx.x >> 4;          // rowgroup (16 batch rows)
  const int row0 = r * 16;
  const int kg = l >> 4;

  // W_hh slice -> bf16 register fragments (persistent, 128 VGPRs)
  bf16x8 wfrag[16][2];
#pragma unroll
  for (int kk = 0; kk < 16; ++kk) {
#pragma unroll
    for (int n = 0; n < 2; ++n) {
      const int wrow = w * 512 + c * 32 + n * 16 + (l & 15);
      wfrag[kk][n] = cvt8(W_hh + (size_t)wrow * 512 + kk * 32 + kg * 8);
    }
  }
  for (int e = tid; e < 512; e += 256) ctS[e >> 5][e & 31] = 0.f;
  __syncthreads();

  for (int t = 0; t < 200; ++t) {
    // ---- rowgroup barrier: all 16 peers finished step t-1
    if (t > 0) {
      if (tid == 0) {
        const uint32_t target = (uint32_t)(16 * t);
        while (__hip_atomic_load(cnt + r, __ATOMIC_ACQUIRE, __HIP_MEMORY_SCOPE_AGENT) < target)
          __builtin_amdgcn_s_sleep(2);
      }
      __syncthreads();
    }
    // ---- stage gated ht (16 rows x 512 bf16) -> LDS, swizzled
    const uint16_t* hb = hbuf + (size_t)(t & 1) * (256 * 512);
#pragma unroll
    for (int i = 0; i < 8; ++i) {
      const int chunk = tid + i * 256;   // 2048 x 8B
      const int rr = chunk >> 7;
      const int o8 = chunk & 127;
      uint64_t v = __hip_atomic_load(
          (const uint64_t*)(hb + (size_t)(row0 + rr) * 512) + o8,
          __ATOMIC_RELAXED, __HIP_MEMORY_SCOPE_AGENT);
      *(uint64_t*)((char*)htgS + rr * 1024 + ((o8 * 8) ^ ((rr & 7) << 4))) = v;
    }
    __syncthreads();

    // ---- gates = encW[input] + htg @ W_hh_slice^T  (16 rows x 32 cols/wave)
    f32x4 acc[2];
#pragma unroll
    for (int n = 0; n < 2; ++n) {
#pragma unroll
      for (int j = 0; j < 4; ++j) {
        const int b = row0 + kg * 4 + j;
        const int idx = inp[b * 200 + t];
        acc[n][j] = encW[(size_t)idx * 2048 + w * 512 + c * 32 + n * 16 + (l & 15)];
      }
    }
    const int ar = l & 15;
#pragma unroll
    for (int kk = 0; kk < 16; ++kk) {
      bf16x8 a = *(const bf16x8*)((char*)htgS + ar * 1024 +
                                  ((kk * 64 + kg * 16) ^ ((ar & 7) << 4)));
      acc[0] = MFMA16(a, wfrag[kk][0], acc[0]);
      acc[1] = MFMA16(a, wfrag[kk][1], acc[1]);
    }
#pragma unroll
    for (int n = 0; n < 2; ++n)
#pragma unroll
      for (int j = 0; j < 4; ++j)
        gbuf[w][kg * 4 + j][n * 16 + (l & 15)] = acc[n][j];
    __syncthreads();

    // ---- cell update: thread -> (row, 2 consecutive h)
    {
      const int rr = tid >> 4;
      const int h2 = (tid & 15) << 1;
      const int b = row0 + rr;
      float hv[2];
#pragma unroll
      for (int p = 0; p < 2; ++p) {
        const int h = h2 + p;
        const float ig = sigf(gbuf[0][rr][h]);
        const float fg = sigf(gbuf[1][rr][h]);
        const float gg = tanhfast(gbuf[2][rr][h]);
        const float og = sigf(gbuf[3][rr][h]);
        const float cv = fg * ctS[rr][h] + ig * gg;
        ctS[rr][h] = cv;
        hv[p] = og * tanhfast(cv);
      }
      if (t < 199) {
        // pre-gate for step t+1: htg = ht * sigmoid(ext[:, t+1, :])
        const uint32_t ep = *(const uint32_t*)(ext + (size_t)b * 200 * 512 +
                                               (size_t)(t + 1) * 512 + c * 32 + h2);
        const float g0 = sigf(bf2f((uint16_t)(ep & 0xFFFFu)));
        const float g1 = sigf(bf2f((uint16_t)(ep >> 16)));
        const uint32_t pk = (uint32_t)f2bf(hv[0] * g0) | ((uint32_t)f2bf(hv[1] * g1) << 16);
        uint16_t* hw = hbuf + (size_t)((t + 1) & 1) * (256 * 512) + (size_t)b * 512 + c * 32 + h2;
        __hip_atomic_store((uint32_t*)hw, pk, __ATOMIC_RELAXED, __HIP_MEMORY_SCOPE_AGENT);
      } else {
        hfinal[(size_t)b * 512 + c * 32 + h2]     = hv[0];
        hfinal[(size_t)b * 512 + c * 32 + h2 + 1] = hv[1];
      }
    }
    __threadfence();
    __syncthreads();
    if (tid == 0)
      __hip_atomic_fetch_add(cnt + r, 1u, __ATOMIC_RELEASE, __HIP_MEMORY_SCOPE_AGENT);
  }
}

// ---------------------------------------------------------------------------
// K4: out[b] = sigmoid( dot(hfinal[b], dec_W[tgt[b]]) + dec_b[tgt[b]] )
// ---------------------------------------------------------------------------
__global__ __launch_bounds__(256) void k_dec(
    const float* __restrict__ hfinal,   // [256][512]
    const float* __restrict__ dec_W,    // [500][512]
    const float* __restrict__ dec_b,    // [500]
    const int* __restrict__ tgt,        // [256]
    float* __restrict__ out)            // [256]
{
  const int w = threadIdx.x >> 6, l = threadIdx.x & 63;
  const int b = blockIdx.x * 4 + w;
  const int t = tgt[b];
  float s = 0.f;
#pragma unroll
  for (int i = 0; i < 8; ++i) {
    const int k = l + i * 64;
    s += hfinal[(size_t)b * 512 + k] * dec_W[(size_t)t * 512 + k];
  }
#pragma unroll
  for (int m = 32; m; m >>= 1) s += __shfl_xor(s, m, 64);
  if (l == 0) out[b] = sigf(s + dec_b[t]);
}

// ---------------------------------------------------------------------------
extern "C" void kernel_launch(void* const* d_in, const int* in_sizes, int n_in,
                              void* d_out, int out_size, void* d_ws, size_t ws_size,
                              hipStream_t stream) {
  (void)in_sizes; (void)n_in; (void)out_size; (void)ws_size;
  const int*   inp       = (const int*)d_in[0];
  const int*   target_id = (const int*)d_in[1];
  const int*   uid       = (const int*)d_in[2];
  const int*   sid       = (const int*)d_in[3];
  // d_in[4] attempt_sequence: unused by reference
  const float* enc_emb   = (const float*)d_in[5];
  const float* user_emb  = (const float*)d_in[6];
  const float* skill_emb = (const float*)d_in[7];
  const float* mf_W      = (const float*)d_in[8];
  const float* mf_b      = (const float*)d_in[9];
  const float* W_ih      = (const float*)d_in[10];
  const float* W_hh      = (const float*)d_in[11];
  const float* b_ih      = (const float*)d_in[12];
  const float* b_hh      = (const float*)d_in[13];
  const float* dec_W     = (const float*)d_in[14];
  const float* dec_b     = (const float*)d_in[15];

  char* ws = (char*)d_ws;
  uint32_t* cnt    = (uint32_t*)(ws);                  //       256 B (16 used)
  uint16_t* hbuf   = (uint16_t*)(ws + 256);            //   524,288 B
  float*    hfinal = (float*)   (ws + 524544);         //   524,288 B
  float*    encW   = (float*)   (ws + 1048832);        // 8,208,384 B
  uint16_t* mfWb   = (uint16_t*)(ws + 9257216);        // 1,048,576 B
  uint16_t* ext    = (uint16_t*)(ws + 10305792);       // 52,428,800 B (total ~59.8 MB)

  // zero barrier counters + hbuf (htg for t=0 must be 0 since h0 = 0)
  hipMemsetAsync(ws, 0, 256 + 524288, stream);

  k_prep<<<2048, 256, 0, stream>>>(mf_W, mfWb);
  k_encW<<<512,  256, 0, stream>>>(enc_emb, W_ih, b_ih, b_hh, encW);
  k_ext <<<800,  256, 0, stream>>>(uid, sid, user_emb, skill_emb, mfWb, mf_b, ext);
  k_scan<<<256,  256, 0, stream>>>(inp, W_hh, encW, ext, hbuf, hfinal, cnt);
  k_dec <<<64,   256, 0, stream>>>(hfinal, dec_W, dec_b, target_id, (float*)d_out);
}

// Round 3
// 2652.210 us; speedup vs baseline: 2.5947x; 2.5947x over previous
//
#include <hip/hip_runtime.h>
#include <stdint.h>

typedef __bf16 bf16x8 __attribute__((ext_vector_type(8)));
typedef float f32x4 __attribute__((ext_vector_type(4)));

#define MFMA16(a, b, c) __builtin_amdgcn_mfma_f32_16x16x32_bf16((a), (b), (c), 0, 0, 0)

__device__ __forceinline__ float sigf(float x) { return 1.f / (1.f + __expf(-x)); }
__device__ __forceinline__ float tanhfast(float x) { return 1.f - 2.f / (__expf(2.f * x) + 1.f); }
__device__ __forceinline__ float bf2f(uint16_t u) {
  union { float f; uint32_t i; } v; v.i = ((uint32_t)u) << 16; return v.f;
}
__device__ __forceinline__ uint16_t f2bf(float f) {
  union { float f; uint32_t i; } v; v.f = f;
  return (uint16_t)((v.i + 0x7FFFu + ((v.i >> 16) & 1u)) >> 16);
}
// 8 consecutive f32 -> bf16x8 (RNE); p must be 16B-aligned
__device__ __forceinline__ bf16x8 cvt8(const float* __restrict__ p) {
  f32x4 a = *(const f32x4*)p;
  f32x4 b = *(const f32x4*)(p + 4);
  bf16x8 r;
  r[0] = (__bf16)a[0]; r[1] = (__bf16)a[1]; r[2] = (__bf16)a[2]; r[3] = (__bf16)a[3];
  r[4] = (__bf16)b[0]; r[5] = (__bf16)b[1]; r[6] = (__bf16)b[2]; r[7] = (__bf16)b[3];
  return r;
}

// ---------------------------------------------------------------------------
// K0: mf_W f32 [512][1000] -> bf16 padded [512][1024]
// ---------------------------------------------------------------------------
__global__ __launch_bounds__(256) void k_prep(
    const float* __restrict__ mf_W, uint16_t* __restrict__ mfWb) {
  const int idx = blockIdx.x * 256 + threadIdx.x;   // 524288 total
  const int h = idx >> 10, k = idx & 1023;
  const float v = (k < 1000) ? mf_W[(size_t)h * 1000 + k] : 0.f;
  mfWb[idx] = f2bf(v);
}

// ---------------------------------------------------------------------------
// K1: encW[v][col] = sum_k enc_emb[v][k]*W_ih[col][k] + b_ih[col] + b_hh[col]
// ---------------------------------------------------------------------------
__global__ __launch_bounds__(256) void k_encW(
    const float* __restrict__ enc_emb,   // [1002][512]
    const float* __restrict__ W_ih,      // [2048][512]
    const float* __restrict__ b_ih,
    const float* __restrict__ b_hh,
    float* __restrict__ encW)            // [1002][2048]
{
  const int w = threadIdx.x >> 6, l = threadIdx.x & 63;
  const int mblk = blockIdx.x & 15;
  const int nblk = blockIdx.x >> 4;
  const int kg = l >> 4;
  const int arow = mblk * 64 + w * 16 + (l & 15);
  const bool rowok = arow < 1002;

  f32x4 acc[4] = {};
  for (int kk = 0; kk < 16; ++kk) {
    const int kc = kk * 32 + kg * 8;
    bf16x8 a = {};
    if (rowok) a = cvt8(enc_emb + (size_t)arow * 512 + kc);
#pragma unroll
    for (int n = 0; n < 4; ++n) {
      const int wrow = nblk * 64 + n * 16 + (l & 15);
      bf16x8 b = cvt8(W_ih + (size_t)wrow * 512 + kc);
      acc[n] = MFMA16(a, b, acc[n]);
    }
  }
  const int orow = mblk * 64 + w * 16 + kg * 4;
#pragma unroll
  for (int n = 0; n < 4; ++n) {
    const int col = nblk * 64 + n * 16 + (l & 15);
    const float bias = b_ih[col] + b_hh[col];
#pragma unroll
    for (int j = 0; j < 4; ++j) {
      const int rrow = orow + j;
      if (rrow < 1002) encW[(size_t)rrow * 2048 + col] = acc[n][j] + bias;
    }
  }
}

// ---------------------------------------------------------------------------
// K2: ext GEMM (gathered A, LDS-staged f32->bf16; B = bf16 mfWb in L2)
// ---------------------------------------------------------------------------
__global__ __launch_bounds__(256, 1) void k_ext(
    const int* __restrict__ uid, const int* __restrict__ sid,   // [51200]
    const float* __restrict__ user_emb,    // [50000][500]
    const float* __restrict__ skill_emb,   // [500][500]
    const uint16_t* __restrict__ mfWb,     // [512][1024] bf16
    const float* __restrict__ mf_b,        // [512]
    uint16_t* __restrict__ ext)            // [51200][512] bf16
{
  __shared__ uint16_t As[64 * 40];   // 64 rows, stride 40 bf16 (80B)

  const int tid = threadIdx.x;
  const int w = tid >> 6, l = tid & 63, kg = l >> 4;
  const int mblk = blockIdx.x;

  const int srow = tid >> 2;
  const int kq = (tid & 3) * 8;
  const int m = mblk * 64 + srow;
  const float* up = user_emb + (size_t)uid[m] * 500;
  const float* sp = skill_emb + (size_t)sid[m] * 500;

  f32x4 acc[4][8] = {};

  for (int kk = 0; kk < 32; ++kk) {
    const int e0 = kk * 32 + kq;
    bf16x8 av = {};
    if (e0 + 8 <= 500) {
      av = cvt8(up + e0);
    } else if (e0 == 496) {
      f32x4 a4 = *(const f32x4*)(up + 496);
      f32x4 b4 = *(const f32x4*)sp;
      av[0] = (__bf16)a4[0]; av[1] = (__bf16)a4[1]; av[2] = (__bf16)a4[2]; av[3] = (__bf16)a4[3];
      av[4] = (__bf16)b4[0]; av[5] = (__bf16)b4[1]; av[6] = (__bf16)b4[2]; av[7] = (__bf16)b4[3];
    } else if (e0 < 1000) {
      av = cvt8(sp + (e0 - 500));
    }
    *(bf16x8*)((char*)As + srow * 80 + kq * 2) = av;
    __syncthreads();

    bf16x8 a[4];
#pragma unroll
    for (int rf = 0; rf < 4; ++rf)
      a[rf] = *(const bf16x8*)((char*)As + (rf * 16 + (l & 15)) * 80 + kg * 16);
#pragma unroll
    for (int n = 0; n < 8; ++n) {
      const int col = w * 128 + n * 16 + (l & 15);
      bf16x8 b = *(const bf16x8*)(mfWb + (size_t)col * 1024 + kk * 32 + kg * 8);
#pragma unroll
      for (int rf = 0; rf < 4; ++rf)
        acc[rf][n] = MFMA16(a[rf], b, acc[rf][n]);
    }
    __syncthreads();
  }

#pragma unroll
  for (int rf = 0; rf < 4; ++rf)
#pragma unroll
    for (int n = 0; n < 8; ++n) {
      const int col = w * 128 + n * 16 + (l & 15);
      const float bias = mf_b[col];
#pragma unroll
      for (int j = 0; j < 4; ++j) {
        const int grow = mblk * 64 + rf * 16 + kg * 4 + j;
        ext[(size_t)grow * 512 + col] = f2bf(acc[rf][n][j] + bias);
      }
    }
}

// ---------------------------------------------------------------------------
// K3: persistent LSTM scan — RELAXED-only cross-block protocol.
//     No acquire/release fences (they emit buffer_inv / buffer_wbl2 on gfx950
//     = full L2 invalidate/writeback per step -> round-2's 33us/step).
//     Ordering: relaxed sc1 stores -> s_waitcnt vmcnt(0) -> syncthreads ->
//     relaxed fetch_add. Consumer: relaxed poll -> syncthreads -> sc1 loads.
// ---------------------------------------------------------------------------
__global__ __launch_bounds__(256, 1) void k_scan(
    const int* __restrict__ inp,        // [256][200]
    const float* __restrict__ W_hh,     // [2048][512] f32
    const float* __restrict__ encW,     // [1002][2048] f32
    const uint16_t* __restrict__ ext,   // [256*200][512] bf16
    uint16_t* __restrict__ hbuf,        // [2][256][512] bf16 (buf0 zeroed)
    float* __restrict__ hfinal,         // [256][512] f32
    uint32_t* __restrict__ cnt)         // [16]
{
  __shared__ uint16_t htgS[16 * 512];   // XOR-swizzled rows of 1024B
  __shared__ float gbuf[4][16][32];
  __shared__ float ctS[16][32];

  const int tid = threadIdx.x;
  const int w = tid >> 6, l = tid & 63;   // wave w = gate (i,f,g,o)
  const int c = blockIdx.x & 15;          // h-slice (32 h)
  const int r = blockIdx.x >> 4;          // rowgroup (16 batch rows)
  const int row0 = r * 16;
  const int kg = l >> 4;

  // W_hh slice -> bf16 register fragments (persistent, 128 VGPRs)
  bf16x8 wfrag[16][2];
#pragma unroll
  for (int kk = 0; kk < 16; ++kk) {
#pragma unroll
    for (int n = 0; n < 2; ++n) {
      const int wrow = w * 512 + c * 32 + n * 16 + (l & 15);
      wfrag[kk][n] = cvt8(W_hh + (size_t)wrow * 512 + kk * 32 + kg * 8);
    }
  }
  for (int e = tid; e < 512; e += 256) ctS[e >> 5][e & 31] = 0.f;

  // roles for cell-update phase
  const int urr = tid >> 4;             // row within group
  const int uh2 = (tid & 15) << 1;      // 2 consecutive h
  const int ub = row0 + urr;

  // ---- prefetch for t=0: encW gather (acc) + ext gate bits
  f32x4 acc[2];
#pragma unroll
  for (int n = 0; n < 2; ++n)
#pragma unroll
    for (int j = 0; j < 4; ++j) {
      const int b = row0 + kg * 4 + j;
      acc[n][j] = encW[(size_t)inp[b * 200 + 0] * 2048 + w * 512 + c * 32 + n * 16 + (l & 15)];
    }
  uint32_t ep = *(const uint32_t*)(ext + (size_t)ub * 200 * 512 + (size_t)1 * 512 + c * 32 + uh2);

  __syncthreads();

  for (int t = 0; t < 200; ++t) {
    // ---- rowgroup barrier: all 16 peers finished step t-1 (RELAXED poll)
    if (t > 0) {
      if (tid == 0) {
        const uint32_t target = (uint32_t)(16 * t);
        while (__hip_atomic_load(cnt + r, __ATOMIC_RELAXED, __HIP_MEMORY_SCOPE_AGENT) < target)
          __builtin_amdgcn_s_sleep(1);
      }
      __syncthreads();
    }
    // ---- stage gated ht (16 rows x 512 bf16) -> LDS, swizzled
    const uint16_t* hb = hbuf + (size_t)(t & 1) * (256 * 512);
#pragma unroll
    for (int i = 0; i < 8; ++i) {
      const int chunk = tid + i * 256;   // 2048 x 8B
      const int rr = chunk >> 7;
      const int o8 = chunk & 127;
      uint64_t v = __hip_atomic_load(
          (const uint64_t*)(hb + (size_t)(row0 + rr) * 512) + o8,
          __ATOMIC_RELAXED, __HIP_MEMORY_SCOPE_AGENT);
      *(uint64_t*)((char*)htgS + rr * 1024 + ((o8 * 8) ^ ((rr & 7) << 4))) = v;
    }
    __syncthreads();

    // ---- gates = acc(prefetched encW) + htg @ W_hh_slice^T
    const int ar = l & 15;
#pragma unroll
    for (int kk = 0; kk < 16; ++kk) {
      bf16x8 a = *(const bf16x8*)((char*)htgS + ar * 1024 +
                                  ((kk * 64 + kg * 16) ^ ((ar & 7) << 4)));
      acc[0] = MFMA16(a, wfrag[kk][0], acc[0]);
      acc[1] = MFMA16(a, wfrag[kk][1], acc[1]);
    }
#pragma unroll
    for (int n = 0; n < 2; ++n)
#pragma unroll
      for (int j = 0; j < 4; ++j)
        gbuf[w][kg * 4 + j][n * 16 + (l & 15)] = acc[n][j];
    __syncthreads();

    // ---- prefetch for step t+1 (peer-independent; overlaps with VALU+stores)
    const int tn = (t < 199) ? t + 1 : 199;
    const uint32_t ep_cur = ep;
#pragma unroll
    for (int n = 0; n < 2; ++n)
#pragma unroll
      for (int j = 0; j < 4; ++j) {
        const int b = row0 + kg * 4 + j;
        acc[n][j] = encW[(size_t)inp[b * 200 + tn] * 2048 + w * 512 + c * 32 + n * 16 + (l & 15)];
      }
    {
      const int te = (t + 2 < 200) ? t + 2 : 199;
      ep = *(const uint32_t*)(ext + (size_t)ub * 200 * 512 + (size_t)te * 512 + c * 32 + uh2);
    }

    // ---- cell update: thread -> (row urr, 2 consecutive h)
    {
      float hv[2];
#pragma unroll
      for (int p = 0; p < 2; ++p) {
        const int h = uh2 + p;
        const float ig = sigf(gbuf[0][urr][h]);
        const float fg = sigf(gbuf[1][urr][h]);
        const float gg = tanhfast(gbuf[2][urr][h]);
        const float og = sigf(gbuf[3][urr][h]);
        const float cv = fg * ctS[urr][h] + ig * gg;
        ctS[urr][h] = cv;
        hv[p] = og * tanhfast(cv);
      }
      if (t < 199) {
        // pre-gate for step t+1: htg = ht * sigmoid(ext[:, t+1, :])
        const float g0 = sigf(bf2f((uint16_t)(ep_cur & 0xFFFFu)));
        const float g1 = sigf(bf2f((uint16_t)(ep_cur >> 16)));
        const uint32_t pk = (uint32_t)f2bf(hv[0] * g0) | ((uint32_t)f2bf(hv[1] * g1) << 16);
        uint16_t* hw = hbuf + (size_t)((t + 1) & 1) * (256 * 512) + (size_t)ub * 512 + c * 32 + uh2;
        __hip_atomic_store((uint32_t*)hw, pk, __ATOMIC_RELAXED, __HIP_MEMORY_SCOPE_AGENT);
      } else {
        hfinal[(size_t)ub * 512 + c * 32 + uh2]     = hv[0];
        hfinal[(size_t)ub * 512 + c * 32 + uh2 + 1] = hv[1];
      }
    }
    // stores (sc1, write-through to coherence point) ack'd before counter bump
    asm volatile("s_waitcnt vmcnt(0)" ::: "memory");
    __syncthreads();
    if (tid == 0)
      __hip_atomic_fetch_add(cnt + r, 1u, __ATOMIC_RELAXED, __HIP_MEMORY_SCOPE_AGENT);
  }
}

// ---------------------------------------------------------------------------
// K4: out[b] = sigmoid( dot(hfinal[b], dec_W[tgt[b]]) + dec_b[tgt[b]] )
// ---------------------------------------------------------------------------
__global__ __launch_bounds__(256) void k_dec(
    const float* __restrict__ hfinal,   // [256][512]
    const float* __restrict__ dec_W,    // [500][512]
    const float* __restrict__ dec_b,    // [500]
    const int* __restrict__ tgt,        // [256]
    float* __restrict__ out)            // [256]
{
  const int w = threadIdx.x >> 6, l = threadIdx.x & 63;
  const int b = blockIdx.x * 4 + w;
  const int t = tgt[b];
  float s = 0.f;
#pragma unroll
  for (int i = 0; i < 8; ++i) {
    const int k = l + i * 64;
    s += hfinal[(size_t)b * 512 + k] * dec_W[(size_t)t * 512 + k];
  }
#pragma unroll
  for (int m = 32; m; m >>= 1) s += __shfl_xor(s, m, 64);
  if (l == 0) out[b] = sigf(s + dec_b[t]);
}

// ---------------------------------------------------------------------------
extern "C" void kernel_launch(void* const* d_in, const int* in_sizes, int n_in,
                              void* d_out, int out_size, void* d_ws, size_t ws_size,
                              hipStream_t stream) {
  (void)in_sizes; (void)n_in; (void)out_size; (void)ws_size;
  const int*   inp       = (const int*)d_in[0];
  const int*   target_id = (const int*)d_in[1];
  const int*   uid       = (const int*)d_in[2];
  const int*   sid       = (const int*)d_in[3];
  // d_in[4] attempt_sequence: unused by reference
  const float* enc_emb   = (const float*)d_in[5];
  const float* user_emb  = (const float*)d_in[6];
  const float* skill_emb = (const float*)d_in[7];
  const float* mf_W      = (const float*)d_in[8];
  const float* mf_b      = (const float*)d_in[9];
  const float* W_ih      = (const float*)d_in[10];
  const float* W_hh      = (const float*)d_in[11];
  const float* b_ih      = (const float*)d_in[12];
  const float* b_hh      = (const float*)d_in[13];
  const float* dec_W     = (const float*)d_in[14];
  const float* dec_b     = (const float*)d_in[15];

  char* ws = (char*)d_ws;
  uint32_t* cnt    = (uint32_t*)(ws);                  //       256 B (16 used)
  uint16_t* hbuf   = (uint16_t*)(ws + 256);            //   524,288 B
  float*    hfinal = (float*)   (ws + 524544);         //   524,288 B
  float*    encW   = (float*)   (ws + 1048832);        // 8,208,384 B
  uint16_t* mfWb   = (uint16_t*)(ws + 9257216);        // 1,048,576 B
  uint16_t* ext    = (uint16_t*)(ws + 10305792);       // 52,428,800 B (total ~59.8 MB)

  // zero barrier counters + hbuf (htg for t=0 must be 0 since h0 = 0)
  hipMemsetAsync(ws, 0, 256 + 524288, stream);

  k_prep<<<2048, 256, 0, stream>>>(mf_W, mfWb);
  k_encW<<<512,  256, 0, stream>>>(enc_emb, W_ih, b_ih, b_hh, encW);
  k_ext <<<800,  256, 0, stream>>>(uid, sid, user_emb, skill_emb, mfWb, mf_b, ext);
  k_scan<<<256,  256, 0, stream>>>(inp, W_hh, encW, ext, hbuf, hfinal, cnt);
  k_dec <<<64,   256, 0, stream>>>(hfinal, dec_W, dec_b, target_id, (float*)d_out);
}

// Round 4
// 1258.026 us; speedup vs baseline: 5.4702x; 2.1082x over previous
//
#include <hip/hip_runtime.h>
#include <stdint.h>

typedef __bf16 bf16x8 __attribute__((ext_vector_type(8)));
typedef float f32x4 __attribute__((ext_vector_type(4)));

#define MFMA16(a, b, c) __builtin_amdgcn_mfma_f32_16x16x32_bf16((a), (b), (c), 0, 0, 0)

__device__ __forceinline__ float sigf(float x) { return 1.f / (1.f + __expf(-x)); }
__device__ __forceinline__ float tanhfast(float x) { return 1.f - 2.f / (__expf(2.f * x) + 1.f); }
__device__ __forceinline__ float bf2f(uint16_t u) {
  union { float f; uint32_t i; } v; v.i = ((uint32_t)u) << 16; return v.f;
}
__device__ __forceinline__ uint16_t f2bf(float f) {
  union { float f; uint32_t i; } v; v.f = f;
  return (uint16_t)((v.i + 0x7FFFu + ((v.i >> 16) & 1u)) >> 16);
}
// 8 consecutive f32 -> bf16x8 (RNE); p must be 16B-aligned
__device__ __forceinline__ bf16x8 cvt8(const float* __restrict__ p) {
  f32x4 a = *(const f32x4*)p;
  f32x4 b = *(const f32x4*)(p + 4);
  bf16x8 r;
  r[0] = (__bf16)a[0]; r[1] = (__bf16)a[1]; r[2] = (__bf16)a[2]; r[3] = (__bf16)a[3];
  r[4] = (__bf16)b[0]; r[5] = (__bf16)b[1]; r[6] = (__bf16)b[2]; r[7] = (__bf16)b[3];
  return r;
}

// ---------------------------------------------------------------------------
// K0: mf_W f32 [512][1000] -> bf16 padded [512][1024]
// ---------------------------------------------------------------------------
__global__ __launch_bounds__(256) void k_prep(
    const float* __restrict__ mf_W, uint16_t* __restrict__ mfWb) {
  const int idx = blockIdx.x * 256 + threadIdx.x;   // 524288 total
  const int h = idx >> 10, k = idx & 1023;
  const float v = (k < 1000) ? mf_W[(size_t)h * 1000 + k] : 0.f;
  mfWb[idx] = f2bf(v);
}

// ---------------------------------------------------------------------------
// K1: encW[v][col] = sum_k enc_emb[v][k]*W_ih[col][k] + b_ih[col] + b_hh[col]
// ---------------------------------------------------------------------------
__global__ __launch_bounds__(256) void k_encW(
    const float* __restrict__ enc_emb,   // [1002][512]
    const float* __restrict__ W_ih,      // [2048][512]
    const float* __restrict__ b_ih,
    const float* __restrict__ b_hh,
    float* __restrict__ encW)            // [1002][2048]
{
  const int w = threadIdx.x >> 6, l = threadIdx.x & 63;
  const int mblk = blockIdx.x & 15;
  const int nblk = blockIdx.x >> 4;
  const int kg = l >> 4;
  const int arow = mblk * 64 + w * 16 + (l & 15);
  const bool rowok = arow < 1002;

  f32x4 acc[4] = {};
  for (int kk = 0; kk < 16; ++kk) {
    const int kc = kk * 32 + kg * 8;
    bf16x8 a = {};
    if (rowok) a = cvt8(enc_emb + (size_t)arow * 512 + kc);
#pragma unroll
    for (int n = 0; n < 4; ++n) {
      const int wrow = nblk * 64 + n * 16 + (l & 15);
      bf16x8 b = cvt8(W_ih + (size_t)wrow * 512 + kc);
      acc[n] = MFMA16(a, b, acc[n]);
    }
  }
  const int orow = mblk * 64 + w * 16 + kg * 4;
#pragma unroll
  for (int n = 0; n < 4; ++n) {
    const int col = nblk * 64 + n * 16 + (l & 15);
    const float bias = b_ih[col] + b_hh[col];
#pragma unroll
    for (int j = 0; j < 4; ++j) {
      const int rrow = orow + j;
      if (rrow < 1002) encW[(size_t)rrow * 2048 + col] = acc[n][j] + bias;
    }
  }
}

// ---------------------------------------------------------------------------
// K2: ext GEMM (gathered A, LDS-staged f32->bf16; B = bf16 mfWb in L2)
// ---------------------------------------------------------------------------
__global__ __launch_bounds__(256, 1) void k_ext(
    const int* __restrict__ uid, const int* __restrict__ sid,   // [51200]
    const float* __restrict__ user_emb,    // [50000][500]
    const float* __restrict__ skill_emb,   // [500][500]
    const uint16_t* __restrict__ mfWb,     // [512][1024] bf16
    const float* __restrict__ mf_b,        // [512]
    uint16_t* __restrict__ ext)            // [51200][512] bf16
{
  __shared__ uint16_t As[64 * 40];   // 64 rows, stride 40 bf16 (80B)

  const int tid = threadIdx.x;
  const int w = tid >> 6, l = tid & 63, kg = l >> 4;
  const int mblk = blockIdx.x;

  const int srow = tid >> 2;
  const int kq = (tid & 3) * 8;
  const int m = mblk * 64 + srow;
  const float* up = user_emb + (size_t)uid[m] * 500;
  const float* sp = skill_emb + (size_t)sid[m] * 500;

  f32x4 acc[4][8] = {};

  for (int kk = 0; kk < 32; ++kk) {
    const int e0 = kk * 32 + kq;
    bf16x8 av = {};
    if (e0 + 8 <= 500) {
      av = cvt8(up + e0);
    } else if (e0 == 496) {
      f32x4 a4 = *(const f32x4*)(up + 496);
      f32x4 b4 = *(const f32x4*)sp;
      av[0] = (__bf16)a4[0]; av[1] = (__bf16)a4[1]; av[2] = (__bf16)a4[2]; av[3] = (__bf16)a4[3];
      av[4] = (__bf16)b4[0]; av[5] = (__bf16)b4[1]; av[6] = (__bf16)b4[2]; av[7] = (__bf16)b4[3];
    } else if (e0 < 1000) {
      av = cvt8(sp + (e0 - 500));
    }
    *(bf16x8*)((char*)As + srow * 80 + kq * 2) = av;
    __syncthreads();

    bf16x8 a[4];
#pragma unroll
    for (int rf = 0; rf < 4; ++rf)
      a[rf] = *(const bf16x8*)((char*)As + (rf * 16 + (l & 15)) * 80 + kg * 16);
#pragma unroll
    for (int n = 0; n < 8; ++n) {
      const int col = w * 128 + n * 16 + (l & 15);
      bf16x8 b = *(const bf16x8*)(mfWb + (size_t)col * 1024 + kk * 32 + kg * 8);
#pragma unroll
      for (int rf = 0; rf < 4; ++rf)
        acc[rf][n] = MFMA16(a[rf], b, acc[rf][n]);
    }
    __syncthreads();
  }

#pragma unroll
  for (int rf = 0; rf < 4; ++rf)
#pragma unroll
    for (int n = 0; n < 8; ++n) {
      const int col = w * 128 + n * 16 + (l & 15);
      const float bias = mf_b[col];
#pragma unroll
      for (int j = 0; j < 4; ++j) {
        const int grow = mblk * 64 + rf * 16 + kg * 4 + j;
        ext[(size_t)grow * 512 + col] = f2bf(acc[rf][n][j] + bias);
      }
    }
}

// ---------------------------------------------------------------------------
// K3: persistent LSTM scan — relaxed-only protocol, PADDED per-block flags.
//     Round-3 lesson: 16 counters in ONE 64B line + fetch_add RMW serialized
//     the whole chip. Now: flag[r][c] at 64B stride; signal = plain relaxed
//     store after vmcnt(0)+barrier; poll = wave0, 16 lanes, read-only.
//     Prefetch moved AFTER the signal so its latency hides under the poll.
// ---------------------------------------------------------------------------
__global__ __launch_bounds__(256, 1) void k_scan(
    const int* __restrict__ inp,        // [256][200]
    const float* __restrict__ W_hh,     // [2048][512] f32
    const float* __restrict__ encW,     // [1002][2048] f32
    const uint16_t* __restrict__ ext,   // [256*200][512] bf16
    uint16_t* __restrict__ hbuf,        // [2][256][512] bf16 (buf0 zeroed)
    float* __restrict__ hfinal,         // [256][512] f32
    uint32_t* __restrict__ flags)       // [16][16] padded x16 (64B stride)
{
  __shared__ uint16_t htgS[16 * 512];   // XOR-swizzled rows of 1024B
  __shared__ float gbuf[4][16][32];
  __shared__ float ctS[16][32];
  __shared__ int inpS[16][200];

  const int tid = threadIdx.x;
  const int w = tid >> 6, l = tid & 63;   // wave w = gate (i,f,g,o)
  const int c = blockIdx.x & 15;          // h-slice (32 h)
  const int r = blockIdx.x >> 4;          // rowgroup (16 batch rows)
  const int row0 = r * 16;
  const int kg = l >> 4;

  // W_hh slice -> bf16 register fragments (persistent, 128 VGPRs)
  bf16x8 wfrag[16][2];
#pragma unroll
  for (int kk = 0; kk < 16; ++kk) {
#pragma unroll
    for (int n = 0; n < 2; ++n) {
      const int wrow = w * 512 + c * 32 + n * 16 + (l & 15);
      wfrag[kk][n] = cvt8(W_hh + (size_t)wrow * 512 + kk * 32 + kg * 8);
    }
  }
  for (int e = tid; e < 512; e += 256) ctS[e >> 5][e & 31] = 0.f;
  for (int e = tid; e < 16 * 200; e += 256)
    inpS[e / 200][e % 200] = inp[(row0 + e / 200) * 200 + (e % 200)];

  // roles for cell-update phase
  const int urr = tid >> 4;             // row within group
  const int uh2 = (tid & 15) << 1;      // 2 consecutive h
  const int ub = row0 + urr;

  __syncthreads();

  // ---- prefetch for t=0: encW gather (acc) + ext gate bits (for t=0 update)
  f32x4 acc[2];
#pragma unroll
  for (int n = 0; n < 2; ++n)
#pragma unroll
    for (int j = 0; j < 4; ++j)
      acc[n][j] = encW[(size_t)inpS[kg * 4 + j][0] * 2048 + w * 512 + c * 32 + n * 16 + (l & 15)];
  uint32_t ep = *(const uint32_t*)(ext + (size_t)ub * 200 * 512 + (size_t)1 * 512 + c * 32 + uh2);

  for (int t = 0; t < 200; ++t) {
    // ---- rowgroup barrier: all 16 peers finished step t-1 (padded flags)
    if (t > 0) {
      if (w == 0) {
        const uint32_t target = (uint32_t)t;
        const uint32_t* fb = flags + r * 256;   // 16 flags, 64B apart
        while (true) {
          uint32_t f = target;
          if (l < 16)
            f = __hip_atomic_load(fb + l * 16, __ATOMIC_RELAXED, __HIP_MEMORY_SCOPE_AGENT);
          if (__all((int)(f >= target))) break;
          __builtin_amdgcn_s_sleep(1);
        }
      }
      __syncthreads();
    }
    // ---- stage gated ht (16 rows x 512 bf16) -> LDS, swizzled
    const uint16_t* hb = hbuf + (size_t)(t & 1) * (256 * 512);
#pragma unroll
    for (int i = 0; i < 8; ++i) {
      const int chunk = tid + i * 256;   // 2048 x 8B
      const int rr = chunk >> 7;
      const int o8 = chunk & 127;
      uint64_t v = __hip_atomic_load(
          (const uint64_t*)(hb + (size_t)(row0 + rr) * 512) + o8,
          __ATOMIC_RELAXED, __HIP_MEMORY_SCOPE_AGENT);
      *(uint64_t*)((char*)htgS + rr * 1024 + ((o8 * 8) ^ ((rr & 7) << 4))) = v;
    }
    __syncthreads();

    // ---- gates = acc(prefetched encW) + htg @ W_hh_slice^T
    const int ar = l & 15;
#pragma unroll
    for (int kk = 0; kk < 16; ++kk) {
      bf16x8 a = *(const bf16x8*)((char*)htgS + ar * 1024 +
                                  ((kk * 64 + kg * 16) ^ ((ar & 7) << 4)));
      acc[0] = MFMA16(a, wfrag[kk][0], acc[0]);
      acc[1] = MFMA16(a, wfrag[kk][1], acc[1]);
    }
#pragma unroll
    for (int n = 0; n < 2; ++n)
#pragma unroll
      for (int j = 0; j < 4; ++j)
        gbuf[w][kg * 4 + j][n * 16 + (l & 15)] = acc[n][j];
    __syncthreads();

    // ---- cell update: thread -> (row urr, 2 consecutive h)
    {
      float hv[2];
#pragma unroll
      for (int p = 0; p < 2; ++p) {
        const int h = uh2 + p;
        const float ig = sigf(gbuf[0][urr][h]);
        const float fg = sigf(gbuf[1][urr][h]);
        const float gg = tanhfast(gbuf[2][urr][h]);
        const float og = sigf(gbuf[3][urr][h]);
        const float cv = fg * ctS[urr][h] + ig * gg;
        ctS[urr][h] = cv;
        hv[p] = og * tanhfast(cv);
      }
      if (t < 199) {
        // pre-gate for step t+1: htg = ht * sigmoid(ext[:, t+1, :])
        const float g0 = sigf(bf2f((uint16_t)(ep & 0xFFFFu)));
        const float g1 = sigf(bf2f((uint16_t)(ep >> 16)));
        const uint32_t pk = (uint32_t)f2bf(hv[0] * g0) | ((uint32_t)f2bf(hv[1] * g1) << 16);
        uint16_t* hw = hbuf + (size_t)((t + 1) & 1) * (256 * 512) + (size_t)ub * 512 + c * 32 + uh2;
        __hip_atomic_store((uint32_t*)hw, pk, __ATOMIC_RELAXED, __HIP_MEMORY_SCOPE_AGENT);
      } else {
        hfinal[(size_t)ub * 512 + c * 32 + uh2]     = hv[0];
        hfinal[(size_t)ub * 512 + c * 32 + uh2 + 1] = hv[1];
      }
    }
    // all waves drain their stores to the coherence point, then one flag store
    asm volatile("s_waitcnt vmcnt(0)" ::: "memory");
    __syncthreads();
    if (tid == 0)
      __hip_atomic_store(flags + (r * 16 + c) * 16, (uint32_t)(t + 1),
                         __ATOMIC_RELAXED, __HIP_MEMORY_SCOPE_AGENT);

    // ---- prefetch for step t+1 (off the signal path; hides under next poll)
    if (t < 199) {
      const int tn = t + 1;
#pragma unroll
      for (int n = 0; n < 2; ++n)
#pragma unroll
        for (int j = 0; j < 4; ++j)
          acc[n][j] = encW[(size_t)inpS[kg * 4 + j][tn] * 2048 + w * 512 + c * 32 + n * 16 + (l & 15)];
      const int te = (t + 2 < 200) ? t + 2 : 199;
      ep = *(const uint32_t*)(ext + (size_t)ub * 200 * 512 + (size_t)te * 512 + c * 32 + uh2);
    }
  }
}

// ---------------------------------------------------------------------------
// K4: out[b] = sigmoid( dot(hfinal[b], dec_W[tgt[b]]) + dec_b[tgt[b]] )
// ---------------------------------------------------------------------------
__global__ __launch_bounds__(256) void k_dec(
    const float* __restrict__ hfinal,   // [256][512]
    const float* __restrict__ dec_W,    // [500][512]
    const float* __restrict__ dec_b,    // [500]
    const int* __restrict__ tgt,        // [256]
    float* __restrict__ out)            // [256]
{
  const int w = threadIdx.x >> 6, l = threadIdx.x & 63;
  const int b = blockIdx.x * 4 + w;
  const int t = tgt[b];
  float s = 0.f;
#pragma unroll
  for (int i = 0; i < 8; ++i) {
    const int k = l + i * 64;
    s += hfinal[(size_t)b * 512 + k] * dec_W[(size_t)t * 512 + k];
  }
#pragma unroll
  for (int m = 32; m; m >>= 1) s += __shfl_xor(s, m, 64);
  if (l == 0) out[b] = sigf(s + dec_b[t]);
}

// ---------------------------------------------------------------------------
extern "C" void kernel_launch(void* const* d_in, const int* in_sizes, int n_in,
                              void* d_out, int out_size, void* d_ws, size_t ws_size,
                              hipStream_t stream) {
  (void)in_sizes; (void)n_in; (void)out_size; (void)ws_size;
  const int*   inp       = (const int*)d_in[0];
  const int*   target_id = (const int*)d_in[1];
  const int*   uid       = (const int*)d_in[2];
  const int*   sid       = (const int*)d_in[3];
  // d_in[4] attempt_sequence: unused by reference
  const float* enc_emb   = (const float*)d_in[5];
  const float* user_emb  = (const float*)d_in[6];
  const float* skill_emb = (const float*)d_in[7];
  const float* mf_W      = (const float*)d_in[8];
  const float* mf_b      = (const float*)d_in[9];
  const float* W_ih      = (const float*)d_in[10];
  const float* W_hh      = (const float*)d_in[11];
  const float* b_ih      = (const float*)d_in[12];
  const float* b_hh      = (const float*)d_in[13];
  const float* dec_W     = (const float*)d_in[14];
  const float* dec_b     = (const float*)d_in[15];

  char* ws = (char*)d_ws;
  uint32_t* flags  = (uint32_t*)(ws);                  //    16,384 B (padded flags)
  uint16_t* hbuf   = (uint16_t*)(ws + 16384);          //   524,288 B
  float*    hfinal = (float*)   (ws + 540672);         //   524,288 B
  float*    encW   = (float*)   (ws + 1064960);        // 8,208,384 B
  uint16_t* mfWb   = (uint16_t*)(ws + 9273344);        // 1,048,576 B
  uint16_t* ext    = (uint16_t*)(ws + 10321920);       // 52,428,800 B (total ~62.8 MB)

  // zero flags + hbuf (htg for t=0 must be 0 since h0 = 0)
  hipMemsetAsync(ws, 0, 16384 + 524288, stream);

  k_prep<<<2048, 256, 0, stream>>>(mf_W, mfWb);
  k_encW<<<512,  256, 0, stream>>>(enc_emb, W_ih, b_ih, b_hh, encW);
  k_ext <<<800,  256, 0, stream>>>(uid, sid, user_emb, skill_emb, mfWb, mf_b, ext);
  k_scan<<<256,  256, 0, stream>>>(inp, W_hh, encW, ext, hbuf, hfinal, flags);
  k_dec <<<64,   256, 0, stream>>>(hfinal, dec_W, dec_b, target_id, (float*)d_out);
}